// Round 1
// baseline (3683.111 us; speedup 1.0000x reference)
//
#include <hip/hip_runtime.h>

typedef _Float16 f16;
typedef __attribute__((ext_vector_type(8))) _Float16 f16x8;
typedef __attribute__((ext_vector_type(16))) float f32x16;

#define MFMA32 __builtin_amdgcn_mfma_f32_32x32x16_f16

// geometry
#define TLEN 256
#define BATCH 256
#define HIDN 1024
#define OUTD 768

static constexpr int SMEM_BYTES = (8*4352 + 64*68) * 4;  // 139264 + 17408 = 156672 < 160KiB

__device__ __forceinline__ f16x8 ldf(const f16* p){
  return *reinterpret_cast<const f16x8*>(p);
}
__device__ __forceinline__ float sigm(float x){ return 1.0f/(1.0f + __expf(-x)); }
__device__ __forceinline__ float tanh_(float x){ return 1.0f - 2.0f/(1.0f + __expf(2.0f*x)); }

// Cross-wave K-split reduce: 8 waves each hold a [64m x 64n] fp32 partial in
// acc[2][2] (32x32x16 C-layout: n=lane&31, m=(reg&3)+8*(reg>>2)+4*(lane>>5)).
// Row pitch 68 floats (odd multiple of 4) makes both the float4 stores and the
// phase-1 reads hit the 8-lanes-per-bank-group floor (no excess conflicts).
__device__ __forceinline__ void reduce_to_F(float* red, float* F,
    const f32x16 (&acc)[2][2], int w, int lo, int hi, int tid)
{
  #pragma unroll
  for (int mt = 0; mt < 2; ++mt){
    #pragma unroll
    for (int nt = 0; nt < 2; ++nt){
      int n = nt*32 + lo;
      #pragma unroll
      for (int q = 0; q < 4; ++q){
        int slot = mt*8 + 2*q + hi;           // m-quad index, m0 = 4*slot
        float4 v = make_float4(acc[mt][nt][4*q+0], acc[mt][nt][4*q+1],
                               acc[mt][nt][4*q+2], acc[mt][nt][4*q+3]);
        *reinterpret_cast<float4*>(red + w*4352 + n*68 + slot*4) = v;
      }
    }
  }
  __syncthreads();
  int n = tid >> 3, mqb = tid & 7;
  #pragma unroll
  for (int hh = 0; hh < 2; ++hh){
    int mq = mqb + hh*8;
    float4 s = make_float4(0.f, 0.f, 0.f, 0.f);
    #pragma unroll
    for (int w2 = 0; w2 < 8; ++w2){
      float4 v = *reinterpret_cast<const float4*>(red + w2*4352 + n*68 + mq*4);
      s.x += v.x; s.y += v.y; s.z += v.z; s.w += v.w;
    }
    int m0 = mq*4;
    F[(m0+0)*68 + n] = s.x;
    F[(m0+1)*68 + n] = s.y;
    F[(m0+2)*68 + n] = s.z;
    F[(m0+3)*68 + n] = s.w;
  }
  __syncthreads();
}

// Gates: F[m=batch_local][n = hu_local*4 + gate] holds {r_pre, z_pre, i_n, h_n}
__device__ __forceinline__ void gates_epilogue(const float* F, const float* bias,
    float* h32, f16* hOut, int bb, int cc, int tid)
{
  int b = tid >> 3, hu2 = (tid & 7)*2;
  #pragma unroll
  for (int u = 0; u < 2; ++u){
    int hu_l = hu2 + u;
    float4 g4 = *reinterpret_cast<const float4*>(F + b*68 + hu_l*4);
    float4 bi = *reinterpret_cast<const float4*>(bias + cc*64 + hu_l*4);
    float r  = sigm(g4.x + bi.x);
    float z  = sigm(g4.y + bi.y);
    float nn = tanh_(g4.z + bi.z + r*(g4.w + bi.w));
    size_t idx = (size_t)(bb*64 + b)*HIDN + (size_t)cc*16 + hu_l;
    float hold = h32[idx];
    float hn = (1.0f - z)*nn + z*hold;
    h32[idx] = hn;
    hOut[idx] = (f16)hn;
  }
}

// ---- per-step folded GRU: G[b, j] = h @ Wstep[j,:]^T  (j = hu_l*4+gate), then gates
__global__ __launch_bounds__(512, 2) void step_kernel(
    const f16* __restrict__ A, const f16* __restrict__ W,
    const float* __restrict__ bias, float* __restrict__ h32,
    f16* __restrict__ hOut)
{
  extern __shared__ float smem[];
  float* red = smem;
  float* F = smem + 8*4352;
  int tid = threadIdx.x;
  int w = tid >> 6, l = tid & 63, lo = l & 31, hi = l >> 5;
  int bb = blockIdx.x >> 6, cc = blockIdx.x & 63;
  int k0 = w*128 + hi*8;

  f16x8 bf[8][2];
  #pragma unroll
  for (int ks = 0; ks < 8; ++ks){
    #pragma unroll
    for (int nt = 0; nt < 2; ++nt)
      bf[ks][nt] = ldf(W + (size_t)(cc*64 + nt*32 + lo)*HIDN + k0 + ks*16);
  }
  f32x16 zero = {0,0,0,0,0,0,0,0,0,0,0,0,0,0,0,0};
  f32x16 acc[2][2];
  acc[0][0]=zero; acc[0][1]=zero; acc[1][0]=zero; acc[1][1]=zero;

  const f16* Ab = A + (size_t)(bb*64 + lo)*HIDN + k0;
  #pragma unroll
  for (int ks = 0; ks < 8; ++ks){
    f16x8 a0 = ldf(Ab + ks*16);
    f16x8 a1 = ldf(Ab + (size_t)32*HIDN + ks*16);
    acc[0][0] = MFMA32(a0, bf[ks][0], acc[0][0], 0, 0, 0);
    acc[0][1] = MFMA32(a0, bf[ks][1], acc[0][1], 0, 0, 0);
    acc[1][0] = MFMA32(a1, bf[ks][0], acc[1][0], 0, 0, 0);
    acc[1][1] = MFMA32(a1, bf[ks][1], acc[1][1], 0, 0, 0);
  }
  reduce_to_F(red, F, acc, w, lo, hi, tid);
  gates_epilogue(F, bias, h32, hOut, bb, cc, tid);
}

// ---- step 0: unfolded, concat-K [x0(768) | h0(1024)], B gathered from Wih/Whh with gate masks
__global__ __launch_bounds__(512, 2) void step0_kernel(
    const f16* __restrict__ X0, const f16* __restrict__ H0,
    const f16* __restrict__ Wih, const f16* __restrict__ Whh,
    const float* __restrict__ bias0, float* __restrict__ h32,
    f16* __restrict__ hOut)
{
  extern __shared__ float smem[];
  float* red = smem;
  float* F = smem + 8*4352;
  int tid = threadIdx.x;
  int w = tid >> 6, l = tid & 63, lo = l & 31, hi = l >> 5;
  int bb = blockIdx.x >> 6, cc = blockIdx.x & 63;
  int k0w = w*224;

  f16x8 bf[14][2];
  #pragma unroll
  for (int ks = 0; ks < 14; ++ks){
    #pragma unroll
    for (int nt = 0; nt < 2; ++nt){
      int jl = nt*32 + lo;
      int g = jl & 3, hu = cc*16 + (jl >> 2);
      int kb = k0w + ks*16;
      int kk = kb + hi*8;
      f16x8 v = {0,0,0,0,0,0,0,0};
      if (kb < 768){
        if (g < 3) v = ldf(Wih + (size_t)(g*1024 + hu)*768 + kk);        // gi part (gate 3 -> 0)
      } else {
        if (g != 2) v = ldf(Whh + (size_t)(((g==3)?2:g)*1024 + hu)*1024 + (kk - 768)); // gh part
      }
      bf[ks][nt] = v;
    }
  }
  f32x16 zero = {0,0,0,0,0,0,0,0,0,0,0,0,0,0,0,0};
  f32x16 acc[2][2];
  acc[0][0]=zero; acc[0][1]=zero; acc[1][0]=zero; acc[1][1]=zero;

  #pragma unroll
  for (int ks = 0; ks < 14; ++ks){
    int kb = k0w + ks*16;
    f16x8 a0, a1;
    if (kb < 768){
      int kk = kb + hi*8;
      a0 = ldf(X0 + (size_t)(bb*64 + lo)*768 + kk);
      a1 = ldf(X0 + (size_t)(bb*64 + 32 + lo)*768 + kk);
    } else {
      int kk = kb - 768 + hi*8;
      a0 = ldf(H0 + (size_t)(bb*64 + lo)*HIDN + kk);
      a1 = ldf(H0 + (size_t)(bb*64 + 32 + lo)*HIDN + kk);
    }
    acc[0][0] = MFMA32(a0, bf[ks][0], acc[0][0], 0, 0, 0);
    acc[0][1] = MFMA32(a0, bf[ks][1], acc[0][1], 0, 0, 0);
    acc[1][0] = MFMA32(a1, bf[ks][0], acc[1][0], 0, 0, 0);
    acc[1][1] = MFMA32(a1, bf[ks][1], acc[1][1], 0, 0, 0);
  }
  reduce_to_F(red, F, acc, w, lo, hi, tid);
  gates_epilogue(F, bias0, h32, hOut, bb, cc, tid);
}

// ---- Wc = Wih @ Wfc  (K=768), epilogue adds Whh for r/z gates, scatters into Wstep layout
__global__ __launch_bounds__(512, 2) void wc_gemm(
    const f16* __restrict__ Aih, const f16* __restrict__ BfcT,
    const float* __restrict__ Whh, f16* __restrict__ Wstep)
{
  extern __shared__ float smem[];
  float* red = smem;
  float* F = smem + 8*4352;
  int tid = threadIdx.x;
  int w = tid >> 6, l = tid & 63, lo = l & 31, hi = l >> 5;
  int mb = blockIdx.x >> 4, nb = blockIdx.x & 15;   // 48 x 16
  int k0 = w*96 + hi*8;

  f16x8 bf[6][2];
  #pragma unroll
  for (int ks = 0; ks < 6; ++ks){
    #pragma unroll
    for (int nt = 0; nt < 2; ++nt)
      bf[ks][nt] = ldf(BfcT + (size_t)(nb*64 + nt*32 + lo)*768 + k0 + ks*16);
  }
  f32x16 zero = {0,0,0,0,0,0,0,0,0,0,0,0,0,0,0,0};
  f32x16 acc[2][2];
  acc[0][0]=zero; acc[0][1]=zero; acc[1][0]=zero; acc[1][1]=zero;

  const f16* Ab = Aih + (size_t)(mb*64 + lo)*768 + k0;
  #pragma unroll
  for (int ks = 0; ks < 6; ++ks){
    f16x8 a0 = ldf(Ab + ks*16);
    f16x8 a1 = ldf(Ab + (size_t)32*768 + ks*16);
    acc[0][0] = MFMA32(a0, bf[ks][0], acc[0][0], 0, 0, 0);
    acc[0][1] = MFMA32(a0, bf[ks][1], acc[0][1], 0, 0, 0);
    acc[1][0] = MFMA32(a1, bf[ks][0], acc[1][0], 0, 0, 0);
    acc[1][1] = MFMA32(a1, bf[ks][1], acc[1][1], 0, 0, 0);
  }
  reduce_to_F(red, F, acc, w, lo, hi, tid);

  int m_l = tid >> 3, n0 = (tid & 7)*8;
  int m = mb*64 + m_l;
  int g = m >> 10, hu = m & 1023;
  int row = (hu >> 4)*64 + ((hu & 15) << 2) + g;
  f16x8 ov;
  #pragma unroll
  for (int i = 0; i < 8; ++i){
    float v = F[m_l*68 + n0 + i];
    if (g < 2) v += Whh[(size_t)m*1024 + nb*64 + n0 + i];   // pre-sum r/z weights
    ov[i] = (f16)v;
  }
  *reinterpret_cast<f16x8*>(Wstep + (size_t)row*HIDN + nb*64 + n0) = ov;
}

// ---- final Y = H_hist @ Wfc^T + b_fc   [65536,1024]x[1024,768]
__global__ __launch_bounds__(512, 2) void y_gemm(
    const f16* __restrict__ H, const f16* __restrict__ Wfc,
    const float* __restrict__ bfc, float* __restrict__ out)
{
  extern __shared__ float smem[];
  float* red = smem;
  float* F = smem + 8*4352;
  int tid = threadIdx.x;
  int w = tid >> 6, l = tid & 63, lo = l & 31, hi = l >> 5;
  int mb = blockIdx.x / 12, ob = blockIdx.x % 12;   // o fast -> A L2 reuse
  int k0 = w*128 + hi*8;

  f16x8 bf[8][2];
  #pragma unroll
  for (int ks = 0; ks < 8; ++ks){
    #pragma unroll
    for (int nt = 0; nt < 2; ++nt)
      bf[ks][nt] = ldf(Wfc + (size_t)(ob*64 + nt*32 + lo)*HIDN + k0 + ks*16);
  }
  f32x16 zero = {0,0,0,0,0,0,0,0,0,0,0,0,0,0,0,0};
  f32x16 acc[2][2];
  acc[0][0]=zero; acc[0][1]=zero; acc[1][0]=zero; acc[1][1]=zero;

  const f16* Ab = H + (size_t)(mb*64 + lo)*HIDN + k0;
  #pragma unroll
  for (int ks = 0; ks < 8; ++ks){
    f16x8 a0 = ldf(Ab + ks*16);
    f16x8 a1 = ldf(Ab + (size_t)32*HIDN + ks*16);
    acc[0][0] = MFMA32(a0, bf[ks][0], acc[0][0], 0, 0, 0);
    acc[0][1] = MFMA32(a0, bf[ks][1], acc[0][1], 0, 0, 0);
    acc[1][0] = MFMA32(a1, bf[ks][0], acc[1][0], 0, 0, 0);
    acc[1][1] = MFMA32(a1, bf[ks][1], acc[1][1], 0, 0, 0);
  }
  reduce_to_F(red, F, acc, w, lo, hi, tid);

  int m_l = tid >> 3, n0 = (tid & 7)*8;
  float* po = out + (size_t)(mb*64 + m_l)*OUTD + ob*64 + n0;
  float4 v0 = make_float4(F[m_l*68+n0+0] + bfc[ob*64+n0+0],
                          F[m_l*68+n0+1] + bfc[ob*64+n0+1],
                          F[m_l*68+n0+2] + bfc[ob*64+n0+2],
                          F[m_l*68+n0+3] + bfc[ob*64+n0+3]);
  float4 v1 = make_float4(F[m_l*68+n0+4] + bfc[ob*64+n0+4],
                          F[m_l*68+n0+5] + bfc[ob*64+n0+5],
                          F[m_l*68+n0+6] + bfc[ob*64+n0+6],
                          F[m_l*68+n0+7] + bfc[ob*64+n0+7]);
  *reinterpret_cast<float4*>(po) = v0;
  *reinterpret_cast<float4*>(po + 4) = v1;
}

// ---- fp32 -> fp16 casts (+ Wfc transpose, h32 init)
__global__ void cast_all(const float* __restrict__ Wih, const float* __restrict__ Wfc,
    const float* __restrict__ Whh, const float* __restrict__ src,
    const float* __restrict__ hidden,
    f16* __restrict__ Wih16, f16* __restrict__ Wfc16, f16* __restrict__ WfcT16,
    f16* __restrict__ Whh16, f16* __restrict__ X016, f16* __restrict__ H016,
    float* __restrict__ h32)
{
  const int S0 = 3072*768, S1 = 768*1024, S2 = 3072*1024, S3 = 256*768, S4 = 256*1024;
  const int total = S0 + S1 + S2 + S3 + S4;
  for (int i = blockIdx.x*blockDim.x + threadIdx.x; i < total; i += gridDim.x*blockDim.x){
    int j = i;
    if (j < S0){ Wih16[j] = (f16)Wih[j]; continue; }
    j -= S0;
    if (j < S1){
      float v = Wfc[j];
      Wfc16[j] = (f16)v;
      int o = j >> 10, k = j & 1023;
      WfcT16[(size_t)k*768 + o] = (f16)v;
      continue;
    }
    j -= S1;
    if (j < S2){ Whh16[j] = (f16)Whh[j]; continue; }
    j -= S2;
    if (j < S3){ X016[j] = (f16)src[j]; continue; }   // src[0] = first B*OUT floats
    j -= S3;
    float v = hidden[j];
    h32[j] = v;
    H016[j] = (f16)v;
  }
}

// ---- Wstep gate-3 rows (h_n) = cast of Whh[2048+hu]
__global__ void pack_hn(const float* __restrict__ Whh, f16* __restrict__ Wstep){
  int i = blockIdx.x*blockDim.x + threadIdx.x;   // 131072 items x 8 halves
  int hu = i >> 7, kq = (i & 127) << 3;
  const float* p = Whh + (size_t)(2048 + hu)*1024 + kq;
  f16x8 ov;
  #pragma unroll
  for (int j = 0; j < 8; ++j) ov[j] = (f16)p[j];
  int row = (hu >> 4)*64 + ((hu & 15) << 2) + 3;
  *reinterpret_cast<f16x8*>(Wstep + (size_t)row*HIDN + kq) = ov;
}

// ---- biases: bc = Wih@b_fc + b_ih folded per Wstep-row layout (one wave per row)
__global__ void bias_kernel(const float* __restrict__ Wih, const float* __restrict__ bih,
    const float* __restrict__ bhh, const float* __restrict__ bfc,
    float* __restrict__ bias, float* __restrict__ bias0)
{
  int r = blockIdx.x*4 + (threadIdx.x >> 6);
  int l = threadIdx.x & 63;
  int j = r & 63, cc = r >> 6;
  int g = j & 3, hu = cc*16 + (j >> 2);
  float dot = 0.f;
  if (g < 3){
    int m = g*1024 + hu;
    for (int i = l; i < 768; i += 64) dot += Wih[(size_t)m*768 + i] * bfc[i];
    #pragma unroll
    for (int off = 32; off > 0; off >>= 1) dot += __shfl_down(dot, off);
  }
  if (l == 0){
    float bv, b0v;
    if (g < 2){ int m = g*1024 + hu; bv = bih[m] + dot + bhh[m]; b0v = bih[m] + bhh[m]; }
    else if (g == 2){ int m = 2048 + hu; bv = bih[m] + dot; b0v = bih[m]; }
    else { bv = bhh[2048 + hu]; b0v = bv; }
    bias[r] = bv;
    bias0[r] = b0v;
  }
}

extern "C" void kernel_launch(void* const* d_in, const int* in_sizes, int n_in,
                              void* d_out, int out_size, void* d_ws, size_t ws_size,
                              hipStream_t stream)
{
  const float* src    = (const float*)d_in[0];
  const float* hidden = (const float*)d_in[2];
  const float* W_ih   = (const float*)d_in[3];
  const float* W_hh   = (const float*)d_in[4];
  const float* b_ih   = (const float*)d_in[5];
  const float* b_hh   = (const float*)d_in[6];
  const float* W_fc   = (const float*)d_in[7];
  const float* b_fc   = (const float*)d_in[8];
  float* out = (float*)d_out;
  char* ws = (char*)d_ws;

  // workspace layout (all 256B-aligned)
  size_t o = 0;
  f16* Wstep  = (f16*)(ws + o); o += (size_t)4096*1024*2;   // folded+pre-summed step weights
  f16* Wih16  = (f16*)(ws + o); o += (size_t)3072*768*2;
  f16* Wfc16  = (f16*)(ws + o); o += (size_t)768*1024*2;
  f16* WfcT16 = (f16*)(ws + o); o += (size_t)1024*768*2;
  f16* Whh16  = (f16*)(ws + o); o += (size_t)3072*1024*2;
  f16* X016   = (f16*)(ws + o); o += (size_t)256*768*2;
  f16* H016   = (f16*)(ws + o); o += (size_t)256*1024*2;
  float* h32  = (float*)(ws + o); o += (size_t)256*1024*4;
  float* bias = (float*)(ws + o); o += (size_t)4096*4;
  float* bias0= (float*)(ws + o); o += (size_t)4096*4;
  f16* hist   = (f16*)(ws + o); o += (size_t)TLEN*BATCH*HIDN*2;  // hist[t] = h_{t+1}

  // allow >64KB dynamic LDS (HipKittens pattern); idempotent, capture-safe
  (void)hipFuncSetAttribute(reinterpret_cast<const void*>(step_kernel),
      hipFuncAttributeMaxDynamicSharedMemorySize, SMEM_BYTES);
  (void)hipFuncSetAttribute(reinterpret_cast<const void*>(step0_kernel),
      hipFuncAttributeMaxDynamicSharedMemorySize, SMEM_BYTES);
  (void)hipFuncSetAttribute(reinterpret_cast<const void*>(wc_gemm),
      hipFuncAttributeMaxDynamicSharedMemorySize, SMEM_BYTES);
  (void)hipFuncSetAttribute(reinterpret_cast<const void*>(y_gemm),
      hipFuncAttributeMaxDynamicSharedMemorySize, SMEM_BYTES);

  cast_all<<<4096, 256, 0, stream>>>(W_ih, W_fc, W_hh, src, hidden,
      Wih16, Wfc16, WfcT16, Whh16, X016, H016, h32);
  bias_kernel<<<1024, 256, 0, stream>>>(W_ih, b_ih, b_hh, b_fc, bias, bias0);
  wc_gemm<<<768, 512, SMEM_BYTES, stream>>>(Wih16, WfcT16, W_hh, Wstep);
  pack_hn<<<512, 256, 0, stream>>>(W_hh, Wstep);

  step0_kernel<<<256, 512, SMEM_BYTES, stream>>>(X016, H016, Wih16, Whh16, bias0, h32, hist);
  for (int t = 1; t < TLEN; ++t){
    step_kernel<<<256, 512, SMEM_BYTES, stream>>>(
        hist + (size_t)(t-1)*BATCH*HIDN, Wstep, bias, h32,
        hist + (size_t)t*BATCH*HIDN);
  }
  y_gemm<<<12288, 512, SMEM_BYTES, stream>>>(hist, Wfc16, b_fc, out);
}

// Round 3
// 3256.066 us; speedup vs baseline: 1.1312x; 1.1312x over previous
//
#include <hip/hip_runtime.h>

typedef _Float16 f16;
typedef __attribute__((ext_vector_type(8))) _Float16 f16x8;
typedef __attribute__((ext_vector_type(16))) float f32x16;

#define MFMA32 __builtin_amdgcn_mfma_f32_32x32x16_f16

// geometry
#define TLEN 256
#define BATCH 256
#define HIDN 1024
#define OUTD 768

static constexpr int SMEM_BYTES = (8*4352 + 64*68) * 4;  // 156672 for step0/wc/y kernels
static constexpr int PSMEM_BYTES = 98304;                // persistent: forces 1 block/CU

__device__ __forceinline__ f16x8 ldf(const f16* p){
  return *reinterpret_cast<const f16x8*>(p);
}
__device__ __forceinline__ float sigm(float x){ return 1.0f/(1.0f + __expf(-x)); }
__device__ __forceinline__ float tanh_(float x){ return 1.0f - 2.0f/(1.0f + __expf(2.0f*x)); }

// ===================== shared helpers for non-persistent GEMM kernels ==========
__device__ __forceinline__ void reduce_to_F(float* red, float* F,
    const f32x16 (&acc)[2][2], int w, int lo, int hi, int tid)
{
  #pragma unroll
  for (int mt = 0; mt < 2; ++mt){
    #pragma unroll
    for (int nt = 0; nt < 2; ++nt){
      int n = nt*32 + lo;
      #pragma unroll
      for (int q = 0; q < 4; ++q){
        int slot = mt*8 + 2*q + hi;
        float4 v = make_float4(acc[mt][nt][4*q+0], acc[mt][nt][4*q+1],
                               acc[mt][nt][4*q+2], acc[mt][nt][4*q+3]);
        *reinterpret_cast<float4*>(red + w*4352 + n*68 + slot*4) = v;
      }
    }
  }
  __syncthreads();
  int n = tid >> 3, mqb = tid & 7;
  #pragma unroll
  for (int hh = 0; hh < 2; ++hh){
    int mq = mqb + hh*8;
    float4 s = make_float4(0.f, 0.f, 0.f, 0.f);
    #pragma unroll
    for (int w2 = 0; w2 < 8; ++w2){
      float4 v = *reinterpret_cast<const float4*>(red + w2*4352 + n*68 + mq*4);
      s.x += v.x; s.y += v.y; s.z += v.z; s.w += v.w;
    }
    int m0 = mq*4;
    F[(m0+0)*68 + n] = s.x;
    F[(m0+1)*68 + n] = s.y;
    F[(m0+2)*68 + n] = s.z;
    F[(m0+3)*68 + n] = s.w;
  }
  __syncthreads();
}

__device__ __forceinline__ void gates_epilogue(const float* F, const float* bias,
    float* h32, f16* hOut, int bb, int cc, int tid)
{
  int b = tid >> 3, hu2 = (tid & 7)*2;
  #pragma unroll
  for (int u = 0; u < 2; ++u){
    int hu_l = hu2 + u;
    float4 g4 = *reinterpret_cast<const float4*>(F + b*68 + hu_l*4);
    float4 bi = *reinterpret_cast<const float4*>(bias + cc*64 + hu_l*4);
    float r  = sigm(g4.x + bi.x);
    float z  = sigm(g4.y + bi.y);
    float nn = tanh_(g4.z + bi.z + r*(g4.w + bi.w));
    size_t idx = (size_t)(bb*64 + b)*HIDN + (size_t)cc*16 + hu_l;
    float hold = h32[idx];
    float hn = (1.0f - z)*nn + z*hold;
    h32[idx] = hn;
    hOut[idx] = (f16)hn;
  }
}

// ===================== persistent GRU recurrence (t = 1..255) ==================
// Grid 256 blocks (cooperative, 1/CU via 96KB LDS). Block idx: bb=idx&3, cc=idx>>2
// => each XCD (idx%8) hosts exactly one bb -> A slice is single-copy per L2,
// and each bb-group's 64-block barrier spans only 2 XCDs.
// Waves: w=tid>>6; wk=w&3 (K-quarter, 256), wm=w>>2 (m-half, 32 rows).
// W frags (32 x f16x8 = 128 VGPR) are register-resident for the whole kernel.
// h32 carry lives in registers (block-private [64m x 16hu] slice).
__global__ __launch_bounds__(512, 2) void gru_persistent(
    f16* __restrict__ hist, const f16* __restrict__ Wstep,
    const float* __restrict__ bias, const float* __restrict__ h32init,
    unsigned int* __restrict__ ctr)
{
  extern __shared__ float part[];       // [8 waves][32 m][68 pitch] = 69632 B used
  int tid = threadIdx.x;
  int w = tid >> 6, l = tid & 63, lo = l & 31, hi = l >> 5;
  int wk = w & 3, wm = w >> 2;
  int bb = blockIdx.x & 3, cc = blockIdx.x >> 2;
  unsigned int* ctrb = ctr + bb*64;

  // --- register-resident folded weights: rows cc*64 + n, k-slice wk*256 ---
  const f16* Wb = Wstep + (size_t)(cc*64 + lo)*HIDN + wk*256 + hi*8;
  f16x8 bw0[16], bw1[16];
  #pragma unroll
  for (int kc = 0; kc < 16; ++kc){
    bw0[kc] = ldf(Wb + kc*16);                       // n = lo
    bw1[kc] = ldf(Wb + (size_t)32*HIDN + kc*16);     // n = 32 + lo
  }

  // --- reducer-role state: thread owns (m=em, hu = 2e, 2e+1) ---
  int em = tid >> 3, e = tid & 7;
  int wmg = em >> 5, ml = em & 31;
  float4 bi0 = *reinterpret_cast<const float4*>(bias + cc*64 + e*8);
  float4 bi1 = *reinterpret_cast<const float4*>(bias + cc*64 + e*8 + 4);
  size_t hrow = (size_t)(bb*64 + em)*HIDN + (size_t)cc*16 + 2*e;
  float hold0 = h32init[hrow];
  float hold1 = h32init[hrow + 1];

  const f32x16 Z = {0,0,0,0,0,0,0,0,0,0,0,0,0,0,0,0};

  for (int t = 1; t < TLEN; ++t){
    if (t > 1){
      if (tid == 0){
        unsigned target = 64u * (unsigned)(t - 1);
        while (__hip_atomic_load(ctrb, __ATOMIC_RELAXED, __HIP_MEMORY_SCOPE_AGENT) < target)
          __builtin_amdgcn_s_sleep(2);
        __builtin_amdgcn_fence(__ATOMIC_ACQUIRE, "agent");   // inv L1 + XCD L2
      }
      __syncthreads();
    }

    // ---- GEMM: wave computes [32m x 64n] over its K-quarter ----
    const f16* Ab = hist + (size_t)(t-1)*BATCH*HIDN
                  + (size_t)(bb*64 + wm*32 + lo)*HIDN + wk*256 + hi*8;
    f32x16 acc0 = Z, acc1 = Z;
    #pragma unroll
    for (int kc = 0; kc < 16; ++kc){
      f16x8 a = ldf(Ab + kc*16);
      acc0 = MFMA32(a, bw0[kc], acc0, 0, 0, 0);
      acc1 = MFMA32(a, bw1[kc], acc1, 0, 0, 0);
    }

    // ---- partial store [m][n], pitch 68 (2-way bank aliasing = free) ----
    float* pw = part + w*2176;
    #pragma unroll
    for (int r = 0; r < 16; ++r){
      int m_l = (r & 3) + 8*(r >> 2) + 4*hi;
      pw[m_l*68 + lo]      = acc0[r];
      pw[m_l*68 + 32 + lo] = acc1[r];
    }
    __syncthreads();

    // ---- reduce 4 K-partials + gates, fold into h carry ----
    const float* pb = part + (size_t)wmg*4*2176 + ml*68 + e*8;
    float4 g0 = make_float4(0.f,0.f,0.f,0.f), g1 = make_float4(0.f,0.f,0.f,0.f);
    #pragma unroll
    for (int j = 0; j < 4; ++j){
      const float* q = pb + j*2176;
      float4 a = *reinterpret_cast<const float4*>(q);
      float4 b = *reinterpret_cast<const float4*>(q + 4);
      g0.x += a.x; g0.y += a.y; g0.z += a.z; g0.w += a.w;
      g1.x += b.x; g1.y += b.y; g1.z += b.z; g1.w += b.w;
    }
    float r0 = sigm(g0.x + bi0.x), z0 = sigm(g0.y + bi0.y);
    float n0 = tanh_(g0.z + bi0.z + r0*(g0.w + bi0.w));
    float hn0 = (1.f - z0)*n0 + z0*hold0; hold0 = hn0;
    float r1 = sigm(g1.x + bi1.x), z1 = sigm(g1.y + bi1.y);
    float n1 = tanh_(g1.z + bi1.z + r1*(g1.w + bi1.w));
    float hn1 = (1.f - z1)*n1 + z1*hold1; hold1 = hn1;

    unsigned short u0 = __builtin_bit_cast(unsigned short, (f16)hn0);
    unsigned short u1 = __builtin_bit_cast(unsigned short, (f16)hn1);
    unsigned pk = (unsigned)u0 | ((unsigned)u1 << 16);
    // agent-scope store: reaches LLC (cross-XCD coherence point) directly
    __hip_atomic_store(
        reinterpret_cast<unsigned*>(hist + (size_t)t*BATCH*HIDN + hrow),
        pk, __ATOMIC_RELAXED, __HIP_MEMORY_SCOPE_AGENT);

    __syncthreads();   // drains stores (vmcnt 0) + protects LDS reuse

    if (t < TLEN-1 && tid == 0){
      __builtin_amdgcn_fence(__ATOMIC_RELEASE, "agent");
      __hip_atomic_fetch_add(ctrb, 1u, __ATOMIC_RELAXED, __HIP_MEMORY_SCOPE_AGENT);
    }
  }
}

__global__ void init_ctr(unsigned int* c){ c[threadIdx.x] = 0u; }

// ---- step 0: unfolded, concat-K [x0(768) | h0(1024)] ----
__global__ __launch_bounds__(512, 2) void step0_kernel(
    const f16* __restrict__ X0, const f16* __restrict__ H0,
    const f16* __restrict__ Wih, const f16* __restrict__ Whh,
    const float* __restrict__ bias0, float* __restrict__ h32,
    f16* __restrict__ hOut)
{
  extern __shared__ float smem[];
  float* red = smem;
  float* F = smem + 8*4352;
  int tid = threadIdx.x;
  int w = tid >> 6, l = tid & 63, lo = l & 31, hi = l >> 5;
  int bb = blockIdx.x >> 6, cc = blockIdx.x & 63;
  int k0w = w*224;

  f16x8 bf[14][2];
  #pragma unroll
  for (int ks = 0; ks < 14; ++ks){
    #pragma unroll
    for (int nt = 0; nt < 2; ++nt){
      int jl = nt*32 + lo;
      int g = jl & 3, hu = cc*16 + (jl >> 2);
      int kb = k0w + ks*16;
      int kk = kb + hi*8;
      f16x8 v = {0,0,0,0,0,0,0,0};
      if (kb < 768){
        if (g < 3) v = ldf(Wih + (size_t)(g*1024 + hu)*768 + kk);
      } else {
        if (g != 2) v = ldf(Whh + (size_t)(((g==3)?2:g)*1024 + hu)*1024 + (kk - 768));
      }
      bf[ks][nt] = v;
    }
  }
  f32x16 zero = {0,0,0,0,0,0,0,0,0,0,0,0,0,0,0,0};
  f32x16 acc[2][2];
  acc[0][0]=zero; acc[0][1]=zero; acc[1][0]=zero; acc[1][1]=zero;

  #pragma unroll
  for (int ks = 0; ks < 14; ++ks){
    int kb = k0w + ks*16;
    f16x8 a0, a1;
    if (kb < 768){
      int kk = kb + hi*8;
      a0 = ldf(X0 + (size_t)(bb*64 + lo)*768 + kk);
      a1 = ldf(X0 + (size_t)(bb*64 + 32 + lo)*768 + kk);
    } else {
      int kk = kb - 768 + hi*8;
      a0 = ldf(H0 + (size_t)(bb*64 + lo)*HIDN + kk);
      a1 = ldf(H0 + (size_t)(bb*64 + 32 + lo)*HIDN + kk);
    }
    acc[0][0] = MFMA32(a0, bf[ks][0], acc[0][0], 0, 0, 0);
    acc[0][1] = MFMA32(a0, bf[ks][1], acc[0][1], 0, 0, 0);
    acc[1][0] = MFMA32(a1, bf[ks][0], acc[1][0], 0, 0, 0);
    acc[1][1] = MFMA32(a1, bf[ks][1], acc[1][1], 0, 0, 0);
  }
  reduce_to_F(red, F, acc, w, lo, hi, tid);
  gates_epilogue(F, bias0, h32, hOut, bb, cc, tid);
}

// ---- Wc = Wih @ Wfc (K=768), + Whh pre-sum for r/z, scatter to Wstep layout ----
__global__ __launch_bounds__(512, 2) void wc_gemm(
    const f16* __restrict__ Aih, const f16* __restrict__ BfcT,
    const float* __restrict__ Whh, f16* __restrict__ Wstep)
{
  extern __shared__ float smem[];
  float* red = smem;
  float* F = smem + 8*4352;
  int tid = threadIdx.x;
  int w = tid >> 6, l = tid & 63, lo = l & 31, hi = l >> 5;
  int mb = blockIdx.x >> 4, nb = blockIdx.x & 15;
  int k0 = w*96 + hi*8;

  f16x8 bf[6][2];
  #pragma unroll
  for (int ks = 0; ks < 6; ++ks){
    #pragma unroll
    for (int nt = 0; nt < 2; ++nt)
      bf[ks][nt] = ldf(BfcT + (size_t)(nb*64 + nt*32 + lo)*768 + k0 + ks*16);
  }
  f32x16 zero = {0,0,0,0,0,0,0,0,0,0,0,0,0,0,0,0};
  f32x16 acc[2][2];
  acc[0][0]=zero; acc[0][1]=zero; acc[1][0]=zero; acc[1][1]=zero;

  const f16* Ab = Aih + (size_t)(mb*64 + lo)*768 + k0;
  #pragma unroll
  for (int ks = 0; ks < 6; ++ks){
    f16x8 a0 = ldf(Ab + ks*16);
    f16x8 a1 = ldf(Ab + (size_t)32*768 + ks*16);
    acc[0][0] = MFMA32(a0, bf[ks][0], acc[0][0], 0, 0, 0);
    acc[0][1] = MFMA32(a0, bf[ks][1], acc[0][1], 0, 0, 0);
    acc[1][0] = MFMA32(a1, bf[ks][0], acc[1][0], 0, 0, 0);
    acc[1][1] = MFMA32(a1, bf[ks][1], acc[1][1], 0, 0, 0);
  }
  reduce_to_F(red, F, acc, w, lo, hi, tid);

  int m_l = tid >> 3, n0 = (tid & 7)*8;
  int m = mb*64 + m_l;
  int g = m >> 10, hu = m & 1023;
  int row = (hu >> 4)*64 + ((hu & 15) << 2) + g;
  f16x8 ov;
  #pragma unroll
  for (int i = 0; i < 8; ++i){
    float v = F[m_l*68 + n0 + i];
    if (g < 2) v += Whh[(size_t)m*1024 + nb*64 + n0 + i];
    ov[i] = (f16)v;
  }
  *reinterpret_cast<f16x8*>(Wstep + (size_t)row*HIDN + nb*64 + n0) = ov;
}

// ---- final Y = H_hist @ Wfc^T + b_fc ----
__global__ __launch_bounds__(512, 2) void y_gemm(
    const f16* __restrict__ H, const f16* __restrict__ Wfc,
    const float* __restrict__ bfc, float* __restrict__ out)
{
  extern __shared__ float smem[];
  float* red = smem;
  float* F = smem + 8*4352;
  int tid = threadIdx.x;
  int w = tid >> 6, l = tid & 63, lo = l & 31, hi = l >> 5;
  int mb = blockIdx.x / 12, ob = blockIdx.x % 12;
  int k0 = w*128 + hi*8;

  f16x8 bf[8][2];
  #pragma unroll
  for (int ks = 0; ks < 8; ++ks){
    #pragma unroll
    for (int nt = 0; nt < 2; ++nt)
      bf[ks][nt] = ldf(Wfc + (size_t)(ob*64 + nt*32 + lo)*HIDN + k0 + ks*16);
  }
  f32x16 zero = {0,0,0,0,0,0,0,0,0,0,0,0,0,0,0,0};
  f32x16 acc[2][2];
  acc[0][0]=zero; acc[0][1]=zero; acc[1][0]=zero; acc[1][1]=zero;

  const f16* Ab = H + (size_t)(mb*64 + lo)*HIDN + k0;
  #pragma unroll
  for (int ks = 0; ks < 8; ++ks){
    f16x8 a0 = ldf(Ab + ks*16);
    f16x8 a1 = ldf(Ab + (size_t)32*HIDN + ks*16);
    acc[0][0] = MFMA32(a0, bf[ks][0], acc[0][0], 0, 0, 0);
    acc[0][1] = MFMA32(a0, bf[ks][1], acc[0][1], 0, 0, 0);
    acc[1][0] = MFMA32(a1, bf[ks][0], acc[1][0], 0, 0, 0);
    acc[1][1] = MFMA32(a1, bf[ks][1], acc[1][1], 0, 0, 0);
  }
  reduce_to_F(red, F, acc, w, lo, hi, tid);

  int m_l = tid >> 3, n0 = (tid & 7)*8;
  float* po = out + (size_t)(mb*64 + m_l)*OUTD + ob*64 + n0;
  float4 v0 = make_float4(F[m_l*68+n0+0] + bfc[ob*64+n0+0],
                          F[m_l*68+n0+1] + bfc[ob*64+n0+1],
                          F[m_l*68+n0+2] + bfc[ob*64+n0+2],
                          F[m_l*68+n0+3] + bfc[ob*64+n0+3]);
  float4 v1 = make_float4(F[m_l*68+n0+4] + bfc[ob*64+n0+4],
                          F[m_l*68+n0+5] + bfc[ob*64+n0+5],
                          F[m_l*68+n0+6] + bfc[ob*64+n0+6],
                          F[m_l*68+n0+7] + bfc[ob*64+n0+7]);
  *reinterpret_cast<float4*>(po) = v0;
  *reinterpret_cast<float4*>(po + 4) = v1;
}

// ---- fp32 -> fp16 casts (+ Wfc transpose, h32 init) ----
__global__ void cast_all(const float* __restrict__ Wih, const float* __restrict__ Wfc,
    const float* __restrict__ Whh, const float* __restrict__ src,
    const float* __restrict__ hidden,
    f16* __restrict__ Wih16, f16* __restrict__ Wfc16, f16* __restrict__ WfcT16,
    f16* __restrict__ Whh16, f16* __restrict__ X016, f16* __restrict__ H016,
    float* __restrict__ h32)
{
  const int S0 = 3072*768, S1 = 768*1024, S2 = 3072*1024, S3 = 256*768, S4 = 256*1024;
  const int total = S0 + S1 + S2 + S3 + S4;
  for (int i = blockIdx.x*blockDim.x + threadIdx.x; i < total; i += gridDim.x*blockDim.x){
    int j = i;
    if (j < S0){ Wih16[j] = (f16)Wih[j]; continue; }
    j -= S0;
    if (j < S1){
      float v = Wfc[j];
      Wfc16[j] = (f16)v;
      int o = j >> 10, k = j & 1023;
      WfcT16[(size_t)k*768 + o] = (f16)v;
      continue;
    }
    j -= S1;
    if (j < S2){ Whh16[j] = (f16)Whh[j]; continue; }
    j -= S2;
    if (j < S3){ X016[j] = (f16)src[j]; continue; }
    j -= S3;
    float v = hidden[j];
    h32[j] = v;
    H016[j] = (f16)v;
  }
}

__global__ void pack_hn(const float* __restrict__ Whh, f16* __restrict__ Wstep){
  int i = blockIdx.x*blockDim.x + threadIdx.x;
  int hu = i >> 7, kq = (i & 127) << 3;
  const float* p = Whh + (size_t)(2048 + hu)*1024 + kq;
  f16x8 ov;
  #pragma unroll
  for (int j = 0; j < 8; ++j) ov[j] = (f16)p[j];
  int row = (hu >> 4)*64 + ((hu & 15) << 2) + 3;
  *reinterpret_cast<f16x8*>(Wstep + (size_t)row*HIDN + kq) = ov;
}

__global__ void bias_kernel(const float* __restrict__ Wih, const float* __restrict__ bih,
    const float* __restrict__ bhh, const float* __restrict__ bfc,
    float* __restrict__ bias, float* __restrict__ bias0)
{
  int r = blockIdx.x*4 + (threadIdx.x >> 6);
  int l = threadIdx.x & 63;
  int j = r & 63, cc = r >> 6;
  int g = j & 3, hu = cc*16 + (j >> 2);
  float dot = 0.f;
  if (g < 3){
    int m = g*1024 + hu;
    for (int i = l; i < 768; i += 64) dot += Wih[(size_t)m*768 + i] * bfc[i];
    #pragma unroll
    for (int off = 32; off > 0; off >>= 1) dot += __shfl_down(dot, off);
  }
  if (l == 0){
    float bv, b0v;
    if (g < 2){ int m = g*1024 + hu; bv = bih[m] + dot + bhh[m]; b0v = bih[m] + bhh[m]; }
    else if (g == 2){ int m = 2048 + hu; bv = bih[m] + dot; b0v = bih[m]; }
    else { bv = bhh[2048 + hu]; b0v = bv; }
    bias[r] = bv;
    bias0[r] = b0v;
  }
}

extern "C" void kernel_launch(void* const* d_in, const int* in_sizes, int n_in,
                              void* d_out, int out_size, void* d_ws, size_t ws_size,
                              hipStream_t stream)
{
  const float* src    = (const float*)d_in[0];
  const float* hidden = (const float*)d_in[2];
  const float* W_ih   = (const float*)d_in[3];
  const float* W_hh   = (const float*)d_in[4];
  const float* b_ih   = (const float*)d_in[5];
  const float* b_hh   = (const float*)d_in[6];
  const float* W_fc   = (const float*)d_in[7];
  const float* b_fc   = (const float*)d_in[8];
  float* out = (float*)d_out;
  char* ws = (char*)d_ws;

  size_t o = 0;
  f16* Wstep  = (f16*)(ws + o); o += (size_t)4096*1024*2;
  f16* Wih16  = (f16*)(ws + o); o += (size_t)3072*768*2;
  f16* Wfc16  = (f16*)(ws + o); o += (size_t)768*1024*2;
  f16* WfcT16 = (f16*)(ws + o); o += (size_t)1024*768*2;
  f16* Whh16  = (f16*)(ws + o); o += (size_t)3072*1024*2;
  f16* X016   = (f16*)(ws + o); o += (size_t)256*768*2;
  f16* H016   = (f16*)(ws + o); o += (size_t)256*1024*2;
  float* h32  = (float*)(ws + o); o += (size_t)256*1024*4;
  float* bias = (float*)(ws + o); o += (size_t)4096*4;
  float* bias0= (float*)(ws + o); o += (size_t)4096*4;
  f16* hist   = (f16*)(ws + o); o += (size_t)TLEN*BATCH*HIDN*2;
  unsigned int* ctr = (unsigned int*)(ws + o); o += 256*4;

  (void)hipFuncSetAttribute(reinterpret_cast<const void*>(step0_kernel),
      hipFuncAttributeMaxDynamicSharedMemorySize, SMEM_BYTES);
  (void)hipFuncSetAttribute(reinterpret_cast<const void*>(wc_gemm),
      hipFuncAttributeMaxDynamicSharedMemorySize, SMEM_BYTES);
  (void)hipFuncSetAttribute(reinterpret_cast<const void*>(y_gemm),
      hipFuncAttributeMaxDynamicSharedMemorySize, SMEM_BYTES);
  (void)hipFuncSetAttribute(reinterpret_cast<const void*>(gru_persistent),
      hipFuncAttributeMaxDynamicSharedMemorySize, PSMEM_BYTES);

  cast_all<<<4096, 256, 0, stream>>>(W_ih, W_fc, W_hh, src, hidden,
      Wih16, Wfc16, WfcT16, Whh16, X016, H016, h32);
  bias_kernel<<<1024, 256, 0, stream>>>(W_ih, b_ih, b_hh, b_fc, bias, bias0);
  wc_gemm<<<768, 512, SMEM_BYTES, stream>>>(Wih16, WfcT16, W_hh, Wstep);
  pack_hn<<<512, 256, 0, stream>>>(W_hh, Wstep);
  init_ctr<<<1, 256, 0, stream>>>(ctr);

  step0_kernel<<<256, 512, SMEM_BYTES, stream>>>(X016, H016, Wih16, Whh16, bias0, h32, hist);

  void* pargs[] = { (void*)&hist, (void*)&Wstep, (void*)&bias, (void*)&h32, (void*)&ctr };
  (void)hipLaunchCooperativeKernel(reinterpret_cast<void*>(gru_persistent),
      dim3(256), dim3(512), pargs, PSMEM_BYTES, stream);

  y_gemm<<<12288, 512, SMEM_BYTES, stream>>>(hist, Wfc16, b_fc, out);
}